// Round 2
// baseline (371.517 us; speedup 1.0000x reference)
//
#include <hip/hip_runtime.h>

// YOLO loss: S=7, B=2, C=80. preds cell = 90 f32, target cell = 85 f32.
// Output: 4 f32 scalars (coords, obj, noobj, classes), summed over 401408 cells.
//
// R2: LDS-staged tiles. R1 showed 1.78 TB/s @ 22% peak, VALUBusy 2.7%:
// per-lane 360B stride = 64 cache lines per load instr = request-rate wall.
// Stage 64-cell tiles with coalesced float4, consume from LDS.

#define NPRED 90
#define NTGT  85
#define NCLS  80
#define TILE  64
#define BLOCK 256

__device__ __forceinline__ float sgnf(float x) {
    return (x > 0.0f) ? 1.0f : ((x < 0.0f) ? -1.0f : 0.0f);
}

__device__ __forceinline__ float iou_vs_target(
    float acx, float acy, float aw, float ah,
    float bx1, float by1, float bx2, float by2, float area_b)
{
    float ax1 = acx - aw * 0.5f, ay1 = acy - ah * 0.5f;
    float ax2 = acx + aw * 0.5f, ay2 = acy + ah * 0.5f;
    float iw = fmaxf(fminf(ax2, bx2) - fmaxf(ax1, bx1), 0.0f);
    float ih = fmaxf(fminf(ay2, by2) - fmaxf(ay1, by1), 0.0f);
    float inter = iw * ih;
    float area_a = (ax2 - ax1) * (ay2 - ay1);
    return inter / (area_a + area_b - inter);
}

__global__ __launch_bounds__(BLOCK) void yolo_loss_kernel(
    const float* __restrict__ preds, const float* __restrict__ targ,
    float* __restrict__ out, int n_cells, int n_tiles)
{
    __shared__ __align__(16) float sp[TILE * NPRED];  // 23040 B
    __shared__ __align__(16) float st[TILE * NTGT];   // 21760 B

    float coords = 0.0f, objl = 0.0f, noobjl = 0.0f, clsl = 0.0f;

    const int tid = threadIdx.x;
    const int c   = tid & 63;   // cell within tile
    const int sub = tid >> 6;   // wave id: class-field quarter

    for (int tile = blockIdx.x; tile < n_tiles; tile += gridDim.x) {
        int cell0 = tile * TILE;
        int ncell = min(TILE, n_cells - cell0);

        // ---- stage preds tile: coalesced float4 ----
        {
            const float*  gp  = preds + (size_t)cell0 * NPRED;
            const float4* gp4 = (const float4*)gp;   // cell0*360 % 16 == 0
            int nf  = ncell * NPRED;
            int n4  = nf >> 2;
            float4* sp4 = (float4*)sp;
            for (int i = tid; i < n4; i += BLOCK) sp4[i] = gp4[i];
            for (int i = (n4 << 2) + tid; i < nf; i += BLOCK) sp[i] = gp[i];
        }
        // ---- stage targ tile ----
        {
            const float*  gt  = targ + (size_t)cell0 * NTGT;
            const float4* gt4 = (const float4*)gt;   // cell0*340 % 16 == 0
            int nf  = ncell * NTGT;
            int n4  = nf >> 2;
            float4* st4 = (float4*)st;
            for (int i = tid; i < n4; i += BLOCK) st4[i] = gt4[i];
            for (int i = (n4 << 2) + tid; i < nf; i += BLOCK) st[i] = gt[i];
        }
        __syncthreads();

        if (c < ncell) {
            const float* pc = sp + c * NPRED;
            const float* tc = st + c * NTGT;
            float obj = tc[NCLS];  // t[80]

            // classes loss: this wave's 20-field slice
            float cls = 0.0f;
            int f0 = sub * 20;
            #pragma unroll
            for (int f = 0; f < 20; ++f) {
                float d = fmaf(pc[f0 + f], obj, -tc[f0 + f]);
                cls = fmaf(d, d, cls);
            }
            clsl += cls;

            if (sub == 0) {
                // box fields: p[80..89], t[81..84]
                float p80 = pc[80], p81 = pc[81], p82 = pc[82], p83 = pc[83];
                float p84 = pc[84], p85 = pc[85], p86 = pc[86], p87 = pc[87];
                float p88 = pc[88], p89 = pc[89];
                float tcx = tc[81], tcy = tc[82], tw = tc[83], th = tc[84];

                float bx1 = tcx - tw * 0.5f, by1 = tcy - th * 0.5f;
                float bx2 = tcx + tw * 0.5f, by2 = tcy + th * 0.5f;
                float area_b = (bx2 - bx1) * (by2 - by1);

                // box1 = p[86..89], box2 = p[81..84]
                float iou1 = iou_vs_target(p86, p87, p88, p89, bx1, by1, bx2, by2, area_b);
                float iou2 = iou_vs_target(p81, p82, p83, p84, bx1, by1, bx2, by2, area_b);
                bool use2 = iou2 > iou1;  // argmax: tie -> box1

                float pcx = obj * (use2 ? p81 : p86);
                float pw  = obj * (use2 ? p83 : p88);
                float ph  = obj * (use2 ? p84 : p89);

                // center loss uses ONLY cx (ref's [..., :-3] on a 4-vector)
                float dc = pcx - tcx;
                float dw = sgnf(pw) * sqrtf(fabsf(pw) + 1e-6f) - sqrtf(tw);
                float dh = sgnf(ph) * sqrtf(fabsf(ph) + 1e-6f) - sqrtf(th);
                coords = fmaf(dc, dc, coords);
                coords = fmaf(dw, dw, coords);
                coords = fmaf(dh, dh, coords);

                float obj_pred = use2 ? p80 : p85;
                float e1 = fmaf(obj, obj_pred, -obj);
                objl = fmaf(e1, e1, objl);
                float e2 = fmaf(1.0f - obj, obj_pred, -obj);
                noobjl = fmaf(e2, e2, noobjl);
            }
        }
        __syncthreads();
    }

    // ---- wave reduce (64 lanes) ----
    #pragma unroll
    for (int off = 32; off > 0; off >>= 1) {
        coords += __shfl_down(coords, off);
        objl   += __shfl_down(objl, off);
        noobjl += __shfl_down(noobjl, off);
        clsl   += __shfl_down(clsl, off);
    }

    __shared__ float red[4][4];
    int wave = threadIdx.x >> 6;
    int lane = threadIdx.x & 63;
    if (lane == 0) {
        red[0][wave] = coords;
        red[1][wave] = objl;
        red[2][wave] = noobjl;
        red[3][wave] = clsl;
    }
    __syncthreads();
    if (threadIdx.x == 0) {
        float cd = red[0][0] + red[0][1] + red[0][2] + red[0][3];
        float o  = red[1][0] + red[1][1] + red[1][2] + red[1][3];
        float n  = red[2][0] + red[2][1] + red[2][2] + red[2][3];
        float k  = red[3][0] + red[3][1] + red[3][2] + red[3][3];
        atomicAdd(&out[0], 5.0f * cd);  // LAMBDA_COORDS
        atomicAdd(&out[1], o);
        atomicAdd(&out[2], 0.5f * n);   // LAMBDA_NOOBJ
        atomicAdd(&out[3], k);
    }
}

extern "C" void kernel_launch(void* const* d_in, const int* in_sizes, int n_in,
                              void* d_out, int out_size, void* d_ws, size_t ws_size,
                              hipStream_t stream) {
    const float* preds = (const float*)d_in[0];
    const float* targ  = (const float*)d_in[1];
    float* out = (float*)d_out;

    int n_cells = in_sizes[0] / NPRED;              // 401408
    int n_tiles = (n_cells + TILE - 1) / TILE;      // 6272

    hipMemsetAsync(d_out, 0, (size_t)out_size * sizeof(float), stream);

    int blocks = 1568;  // 4 tiles/block; ~3 resident blocks/CU (44.8 KB LDS)
    if (blocks > n_tiles) blocks = n_tiles;
    hipLaunchKernelGGL(yolo_loss_kernel, dim3(blocks), dim3(BLOCK), 0, stream,
                       preds, targ, out, n_cells, n_tiles);
}

// Round 3
// 369.185 us; speedup vs baseline: 1.0063x; 1.0063x over previous
//
#include <hip/hip_runtime.h>

// YOLO loss: S=7, B=2, C=80. preds cell = 90 f32, target cell = 85 f32.
// Output: 4 f32 scalars (coords, obj, noobj, classes) over 401408 cells.
//
// R3: wave-per-cell, lane=field. R1 (thread-per-cell) was L1-request-bound:
// 360B lane stride => 64 lines touched per VMEM instr (~130/cell). R2 (LDS
// tiles) was latency-bound at 2 blocks/CU. Here every global load is a
// coalesced 64-consecutive-float wave load: 4 VMEM instrs/cell (~12 line
// touches). Box fields broadcast to lane 0 via readlane-style shuffles.

#define NPRED 90
#define NTGT  85
#define NCLS  80
#define BLOCK 256

__device__ __forceinline__ float sgnf(float x) {
    return (x > 0.0f) ? 1.0f : ((x < 0.0f) ? -1.0f : 0.0f);
}

struct CellLoads { float p0, p1, t0, t1; };

__device__ __forceinline__ void process_cell(
    const CellLoads& L, int lane,
    float& coords, float& objl, float& noobjl, float& clsl)
{
    float obj = __shfl(L.t1, 16);  // t[80]

    // ---- class loss: field=lane (0..63) + field=64+lane (lane<16) ----
    float d0 = fmaf(L.p0, obj, -L.t0);
    float acc = d0 * d0;
    if (lane < 16) {
        float d1 = fmaf(L.p1, obj, -L.t1);
        acc = fmaf(d1, d1, acc);
    }
    clsl += acc;

    // ---- broadcast box fields (compile-time lanes -> readlane) ----
    float P80 = __shfl(L.p1, 16), P81 = __shfl(L.p1, 17);
    float P82 = __shfl(L.p1, 18), P83 = __shfl(L.p1, 19);
    float P84 = __shfl(L.p1, 20), P85 = __shfl(L.p1, 21);
    float P86 = __shfl(L.p1, 22);
    float P88 = __shfl(L.p1, 24), P89 = __shfl(L.p1, 25);
    float P87 = __shfl(L.p1, 23);
    float tcx = __shfl(L.t1, 17), tcy = __shfl(L.t1, 18);
    float tw  = __shfl(L.t1, 19), th  = __shfl(L.t1, 20);

    if (lane == 0) {
        float bx1 = tcx - tw * 0.5f, by1 = tcy - th * 0.5f;
        float bx2 = tcx + tw * 0.5f, by2 = tcy + th * 0.5f;
        float area_b = (bx2 - bx1) * (by2 - by1);

        // box1 = p[86..89]
        float ax1 = P86 - P88 * 0.5f, ay1 = P87 - P89 * 0.5f;
        float ax2 = P86 + P88 * 0.5f, ay2 = P87 + P89 * 0.5f;
        float iw = fmaxf(fminf(ax2, bx2) - fmaxf(ax1, bx1), 0.0f);
        float ih = fmaxf(fminf(ay2, by2) - fmaxf(ay1, by1), 0.0f);
        float inter1 = iw * ih;
        float area1 = (ax2 - ax1) * (ay2 - ay1);
        float iou1 = inter1 / (area1 + area_b - inter1);

        // box2 = p[81..84]
        float cx1 = P81 - P83 * 0.5f, cy1 = P82 - P84 * 0.5f;
        float cx2 = P81 + P83 * 0.5f, cy2 = P82 + P84 * 0.5f;
        float jw = fmaxf(fminf(cx2, bx2) - fmaxf(cx1, bx1), 0.0f);
        float jh = fmaxf(fminf(cy2, by2) - fmaxf(cy1, by1), 0.0f);
        float inter2 = jw * jh;
        float area2 = (cx2 - cx1) * (cy2 - cy1);
        float iou2 = inter2 / (area2 + area_b - inter2);

        bool use2 = iou2 > iou1;  // argmax: tie -> box1

        float pcx = obj * (use2 ? P81 : P86);
        float pw  = obj * (use2 ? P83 : P88);
        float ph  = obj * (use2 ? P84 : P89);

        // center loss uses ONLY cx (ref's [..., :-3] on a 4-vector)
        float dc = pcx - tcx;
        float dw = sgnf(pw) * sqrtf(fabsf(pw) + 1e-6f) - sqrtf(tw);
        float dh = sgnf(ph) * sqrtf(fabsf(ph) + 1e-6f) - sqrtf(th);
        coords = fmaf(dc, dc, coords);
        coords = fmaf(dw, dw, coords);
        coords = fmaf(dh, dh, coords);

        float obj_pred = use2 ? P80 : P85;  // p[80] : p[85]
        float e1 = fmaf(obj, obj_pred, -obj);
        objl = fmaf(e1, e1, objl);
        float e2 = fmaf(1.0f - obj, obj_pred, -obj);
        noobjl = fmaf(e2, e2, noobjl);
    }
}

__device__ __forceinline__ CellLoads load_cell(
    const float* __restrict__ preds, const float* __restrict__ targ,
    int c, int lane)
{
    const float* p = preds + (size_t)c * NPRED;
    const float* t = targ  + (size_t)c * NTGT;
    CellLoads L;
    L.p0 = p[lane];
    L.p1 = (lane < NPRED - 64) ? p[64 + lane] : 0.0f;  // fields 64..89
    L.t0 = t[lane];
    L.t1 = (lane < NTGT - 64) ? t[64 + lane] : 0.0f;   // fields 64..84
    return L;
}

__global__ __launch_bounds__(BLOCK) void yolo_loss_kernel(
    const float* __restrict__ preds, const float* __restrict__ targ,
    float* __restrict__ out, int n_cells)
{
    const int lane = threadIdx.x & 63;
    const int gw   = blockIdx.x * (BLOCK / 64) + (threadIdx.x >> 6);
    const int W    = gridDim.x * (BLOCK / 64);

    float coords = 0.0f, objl = 0.0f, noobjl = 0.0f, clsl = 0.0f;

    int c = gw * 2;
    for (; c + 1 < n_cells; c += 2 * W) {
        CellLoads A = load_cell(preds, targ, c, lane);
        CellLoads B = load_cell(preds, targ, c + 1, lane);
        process_cell(A, lane, coords, objl, noobjl, clsl);
        process_cell(B, lane, coords, objl, noobjl, clsl);
    }
    if (c < n_cells) {
        CellLoads A = load_cell(preds, targ, c, lane);
        process_cell(A, lane, coords, objl, noobjl, clsl);
    }

    // ---- wave reduce (64 lanes) ----
    #pragma unroll
    for (int off = 32; off > 0; off >>= 1) {
        coords += __shfl_down(coords, off);
        objl   += __shfl_down(objl, off);
        noobjl += __shfl_down(noobjl, off);
        clsl   += __shfl_down(clsl, off);
    }

    __shared__ float red[4][4];
    int wave = threadIdx.x >> 6;
    if (lane == 0) {
        red[0][wave] = coords;
        red[1][wave] = objl;
        red[2][wave] = noobjl;
        red[3][wave] = clsl;
    }
    __syncthreads();
    if (threadIdx.x == 0) {
        float cd = red[0][0] + red[0][1] + red[0][2] + red[0][3];
        float o  = red[1][0] + red[1][1] + red[1][2] + red[1][3];
        float n  = red[2][0] + red[2][1] + red[2][2] + red[2][3];
        float k  = red[3][0] + red[3][1] + red[3][2] + red[3][3];
        atomicAdd(&out[0], 5.0f * cd);  // LAMBDA_COORDS
        atomicAdd(&out[1], o);
        atomicAdd(&out[2], 0.5f * n);   // LAMBDA_NOOBJ
        atomicAdd(&out[3], k);
    }
}

extern "C" void kernel_launch(void* const* d_in, const int* in_sizes, int n_in,
                              void* d_out, int out_size, void* d_ws, size_t ws_size,
                              hipStream_t stream) {
    const float* preds = (const float*)d_in[0];
    const float* targ  = (const float*)d_in[1];
    float* out = (float*)d_out;

    int n_cells = in_sizes[0] / NPRED;  // 401408

    hipMemsetAsync(d_out, 0, (size_t)out_size * sizeof(float), stream);

    // 2048 blocks = 8192 waves -> 8 blocks/CU (32 waves/CU), ~24 pair-iters/wave
    int blocks = 2048;
    hipLaunchKernelGGL(yolo_loss_kernel, dim3(blocks), dim3(BLOCK), 0, stream,
                       preds, targ, out, n_cells);
}